// Round 2
// baseline (311.251 us; speedup 1.0000x reference)
//
#include <hip/hip_runtime.h>
#include <cstdint>
#include <cstddef>

typedef float floatx4 __attribute__((ext_vector_type(4)));
typedef _Float16 half8_t __attribute__((ext_vector_type(8)));
typedef _Float16 half2_t __attribute__((ext_vector_type(2)));

#define AS1 __attribute__((address_space(1)))
#define AS3 __attribute__((address_space(3)))

__device__ __forceinline__ void glds16(const void* g, void* l) {
  __builtin_amdgcn_global_load_lds((const AS1 void*)g, (AS3 void*)l, 16, 0, 0);
}

__device__ __forceinline__ half2_t pkrtz(float a, float b) {
  return __builtin_bit_cast(half2_t, __builtin_amdgcn_cvt_pkrtz(a, b));
}

__device__ __forceinline__ float fast_tanh(float x) {
  // tanh(x) = 1 - 2/(e^{2x}+1); inf-safe (e2=inf -> rcp=0 -> 1; e2=0 -> -1)
  float e2 = __expf(2.f * x);
  return 1.f - 2.f * __builtin_amdgcn_rcpf(e2 + 1.f);
}

// ---- k_prep: fused {memf32->f16 cvt | Wh transpose->f16 | tq = q@Ws} ------
// blocks [0,16384): cvt ; [16384,16640): transpose ; [16640,17664): tq
__global__ __launch_bounds__(256) void k_prep(
    const float* __restrict__ mem, _Float16* __restrict__ memh,
    const float* __restrict__ Wh, _Float16* __restrict__ WhT,
    const float* __restrict__ q, const float* __restrict__ Ws,
    float* __restrict__ tq) {
  __shared__ float sh[64 * 65];
  const int bx = blockIdx.x;
  const int tid = threadIdx.x;
  if (bx < 16384) {
    size_t i = (((size_t)bx << 8) + tid) << 3;
    floatx4 a = *(const floatx4*)(mem + i);
    floatx4 b = *(const floatx4*)(mem + i + 4);
    union { half2_t h2[4]; half8_t h8; } u;
    u.h2[0] = half2_t{(_Float16)a[0], (_Float16)a[1]};
    u.h2[1] = half2_t{(_Float16)a[2], (_Float16)a[3]};
    u.h2[2] = half2_t{(_Float16)b[0], (_Float16)b[1]};
    u.h2[3] = half2_t{(_Float16)b[2], (_Float16)b[3]};
    *(half8_t*)(memh + i) = u.h8;
  } else if (bx < 16640) {
    int bb = bx - 16384;
    int n0 = (bb & 15) << 6, k0 = (bb >> 4) << 6;
    int tx = tid & 63, ty = tid >> 6;
    #pragma unroll
    for (int r = ty; r < 64; r += 4) sh[r * 65 + tx] = Wh[(size_t)(k0 + r) * 1024 + n0 + tx];
    __syncthreads();
    #pragma unroll
    for (int r = ty; r < 64; r += 4)
      WhT[(size_t)(n0 + r) * 1024 + k0 + tx] = (_Float16)sh[tx * 65 + r];
  } else {
    int bb = bx - 16640;
    int d0 = (bb & 15) << 6, b = bb >> 4;
    int dl = tid & 63, kg = tid >> 6;
    float* qs = sh;
    float* red = sh + 1024;  // [4][64]
    for (int k = tid; k < 1024; k += 256) qs[k] = q[(b << 10) + k];
    __syncthreads();
    float acc = 0.f;
    int kbase = kg << 8;
    #pragma unroll 8
    for (int k = 0; k < 256; ++k)
      acc += qs[kbase + k] * Ws[(size_t)(kbase + k) * 1024 + d0 + dl];
    red[(kg << 6) + dl] = acc;
    __syncthreads();
    if (kg == 0)
      tq[(b << 10) + d0 + dl] = red[dl] + red[64 + dl] + red[128 + dl] + red[192 + dl];
  }
}

// ---- K0/K1 standalone (small-ws fallback path) ----------------------------
__global__ void k0_transpose(const float* __restrict__ Wh, _Float16* __restrict__ WhT) {
  __shared__ float t[64][65];
  int k0 = blockIdx.y << 6, n0 = blockIdx.x << 6;
  int tx = threadIdx.x, ty = threadIdx.y;
  #pragma unroll
  for (int r = ty; r < 64; r += 4) t[r][tx] = Wh[(size_t)(k0 + r) * 1024 + n0 + tx];
  __syncthreads();
  #pragma unroll
  for (int r = ty; r < 64; r += 4)
    WhT[(size_t)(n0 + r) * 1024 + k0 + tx] = (_Float16)t[tx][r];
}

__global__ __launch_bounds__(256) void k1_tq(const float* __restrict__ q,
                                             const float* __restrict__ Ws,
                                             float* __restrict__ tq) {
  __shared__ float qs[1024];
  __shared__ float red[4][64];
  int b = blockIdx.y;
  int d0 = blockIdx.x << 6;
  int dl = threadIdx.x & 63, kg = threadIdx.x >> 6;
  for (int k = threadIdx.x; k < 1024; k += 256) qs[k] = q[(b << 10) + k];
  __syncthreads();
  float acc = 0.f;
  int kbase = kg << 8;
  #pragma unroll 8
  for (int k = 0; k < 256; ++k)
    acc += qs[kbase + k] * Ws[(size_t)(kbase + k) * 1024 + d0 + dl];
  red[kg][dl] = acc;
  __syncthreads();
  if (kg == 0)
    tq[(b << 10) + d0 + dl] = red[0][dl] + red[1][dl] + red[2][dl] + red[3][dl];
}

// ---- K2 deep-pipe: 256x256 tile, BK=64, 8 waves, 1-vmcnt/2-barrier group --
// A = memh (32768x1024 f16), BT = WhT (1024x1024 f16 n-major).
// LDS (128 KiB dynamic):
//   A: buf*32768 + (wm*2+rh)*8192 + r6*128 + chunk*16        (r6 in [0,64))
//   B: 65536 + buf*32768 + ch*16384 + wn*4096 + r5*128 + c*16
// Swizzle: chunk_stored = chunk_logical ^ (row & 7) via inverse-swz global
// source (glds dest stays linear); swz applied on the ds_read side.
// Group T: issue ALL 8 stages for tile T+1 into buf[cur^1], then vmcnt(8)
// (waits only tile T's loads, issued one full group ~2048cy earlier ->
// latency covered), one barrier, 64 uninterrupted MFMA (compiler schedules
// ds_read/lgkmcnt interleave), closing barrier (protects buf[cur] from
// group T+1's stages). 2 barriers + 1 counted vmcnt per K-tile.
__global__ __launch_bounds__(512, 2) void k2_8ph(
    const _Float16* __restrict__ Ah, const _Float16* __restrict__ BT,
    const float* __restrict__ tq, const float* __restrict__ v,
    float* __restrict__ partials) {
  extern __shared__ char smem[];
  const int bid = blockIdx.x;
  const int wg = ((bid & 7) << 6) | (bid >> 3);  // bijective XCD swizzle (512 wgs)
  const int mtile = wg >> 2, ntile = wg & 3;
  const int m0 = mtile << 8, n0 = ntile << 8;
  const int tid = threadIdx.x;
  const int w = tid >> 6, lane = tid & 63;
  const int wm = w >> 2, wn = w & 3, quad = lane >> 4, l15 = lane & 15;

  // ds_read byte offsets (sans buf/rh/ch bases)
  int aoff[2][4], boff[2][2];
  #pragma unroll
  for (int ks = 0; ks < 2; ++ks) {
    int swz = ((ks << 2) + quad) ^ (l15 & 7);
    #pragma unroll
    for (int i = 0; i < 4; ++i)
      aoff[ks][i] = (wm << 14) + (((i << 4) + l15) << 7) + (swz << 4);
    #pragma unroll
    for (int j = 0; j < 2; ++j)
      boff[ks][j] = 65536 + (wn << 12) + (((j << 4) + l15) << 7) + (swz << 4);
  }

  // staging: per-thread global src offsets (f16 elems) + wave-uniform LDS dst
  const int rr = tid >> 3, cc = tid & 7;
  const int r5 = rr & 31;
  int aSrc[2][2], bSrc[2][2], dA[2][2], dB[2][2];
  #pragma unroll
  for (int h = 0; h < 2; ++h)
    #pragma unroll
    for (int hm = 0; hm < 2; ++hm) {
      aSrc[h][hm] = ((m0 + (hm << 7) + (h << 6) + rr) << 10) + ((cc ^ (rr & 7)) << 3);
      dA[h][hm] = (((hm << 1) + h) << 13) + (w << 10);
    }
  #pragma unroll
  for (int ch = 0; ch < 2; ++ch)
    #pragma unroll
    for (int is = 0; is < 2; ++is) {
      int wnb = (is << 1) + (rr >> 5);
      bSrc[ch][is] = ((n0 + (wnb << 6) + (ch << 5) + r5) << 10) + ((cc ^ (r5 & 7)) << 3);
      dB[ch][is] = 65536 + (ch << 14) + (is << 13) + (w << 10);
    }

  floatx4 acc[8][4];
  #pragma unroll
  for (int i = 0; i < 8; ++i)
    #pragma unroll
    for (int j = 0; j < 4; ++j) acc[i][j] = floatx4{0.f, 0.f, 0.f, 0.f};

  half8_t af[2][4], bf[2][2][2];

#define STAGE_A(H, KST, OO)                                   \
  glds16(Ah + aSrc[H][0] + (KST), smem + (OO) + dA[H][0]);    \
  glds16(Ah + aSrc[H][1] + (KST), smem + (OO) + dA[H][1]);
#define STAGE_B(CH, KST, OO)                                  \
  glds16(BT + bSrc[CH][0] + (KST), smem + (OO) + dB[CH][0]);  \
  glds16(BT + bSrc[CH][1] + (KST), smem + (OO) + dB[CH][1]);
#define VMCNT8 asm volatile("s_waitcnt vmcnt(8)" ::: "memory");
#define LOAD_AF(CO, RHOFF)                                    \
  _Pragma("unroll")                                           \
  for (int ks_ = 0; ks_ < 2; ++ks_) {                         \
    _Pragma("unroll")                                         \
    for (int i_ = 0; i_ < 4; ++i_)                            \
      af[ks_][i_] = *(const half8_t*)(smem + (CO) + (RHOFF) + aoff[ks_][i_]); \
  }
#define LOAD_BF(CH, CO, CHOFF)                                \
  _Pragma("unroll")                                           \
  for (int ks_ = 0; ks_ < 2; ++ks_) {                         \
    _Pragma("unroll")                                         \
    for (int j_ = 0; j_ < 2; ++j_)                            \
      bf[CH][ks_][j_] = *(const half8_t*)(smem + (CO) + (CHOFF) + boff[ks_][j_]); \
  }
#define MFMAS(RH, CH)                                         \
  _Pragma("unroll")                                           \
  for (int ks_ = 0; ks_ < 2; ++ks_) {                         \
    _Pragma("unroll")                                         \
    for (int i_ = 0; i_ < 4; ++i_) {                          \
      _Pragma("unroll")                                       \
      for (int j_ = 0; j_ < 2; ++j_)                          \
        acc[(RH)*4 + i_][(CH)*2 + j_] = __builtin_amdgcn_mfma_f32_16x16x32_f16( \
            af[ks_][i_], bf[CH][ks_][j_], acc[(RH)*4 + i_][(CH)*2 + j_], 0, 0, 0); \
    }                                                         \
  }
#define GROUPN(CO, OO, KST)                                   \
  STAGE_A(0, KST, OO)                                         \
  STAGE_B(0, KST, OO)                                         \
  STAGE_B(1, KST, OO)                                         \
  STAGE_A(1, KST, OO)                                         \
  VMCNT8                                                      \
  __builtin_amdgcn_s_barrier();                               \
  asm volatile("" ::: "memory");                              \
  __builtin_amdgcn_s_setprio(1);                              \
  LOAD_AF(CO, 0)                                              \
  LOAD_BF(0, CO, 0)                                           \
  MFMAS(0, 0)                                                 \
  LOAD_BF(1, CO, 16384)                                       \
  MFMAS(0, 1)                                                 \
  LOAD_AF(CO, 8192)                                           \
  MFMAS(1, 0)                                                 \
  MFMAS(1, 1)                                                 \
  __builtin_amdgcn_s_setprio(0);                              \
  asm volatile("" ::: "memory");                              \
  __builtin_amdgcn_s_barrier();

  // prologue: stage tile 0 -> buf0 (no wait; group 0's vmcnt(8) covers it)
  STAGE_A(0, 0, 0)
  STAGE_B(0, 0, 0)
  STAGE_B(1, 0, 0)
  STAGE_A(1, 0, 0)

  #pragma unroll 1
  for (int g2 = 0; g2 < 8; ++g2) {
    const int g = g2 << 1;
    const int kst1 = (g + 1) << 6;
    const int kst2 = (g2 == 7) ? (15 << 6) : ((g + 2) << 6);  // clamp: redundant last stage keeps ledger uniform
    GROUPN(0, 32768, kst1)
    GROUPN(32768, 0, kst2)
  }

#undef GROUPN
#undef MFMAS
#undef LOAD_BF
#undef LOAD_AF
#undef VMCNT8
#undef STAGE_B
#undef STAGE_A

  // drain in-flight DMA before the block can exit / LDS reuse
  asm volatile("s_waitcnt vmcnt(0)" ::: "memory");

  // epilogue: tanh(acc + tq) . v, reduce across 16 lanes, write partials
  const int b = m0 >> 9;
  const int colb = n0 + (wn << 6) + l15;
  float tqv[4], vv[4];
  #pragma unroll
  for (int jf = 0; jf < 4; ++jf) {
    int n = colb + (jf << 4);
    tqv[jf] = tq[(b << 10) + n];
    vv[jf] = v[n];
  }
  #pragma unroll
  for (int rf = 0; rf < 8; ++rf) {
    #pragma unroll
    for (int r = 0; r < 4; ++r) {
      float s = 0.f;
      #pragma unroll
      for (int jf = 0; jf < 4; ++jf) s += fast_tanh(acc[rf][jf][r] + tqv[jf]) * vv[jf];
      s += __shfl_xor(s, 1);
      s += __shfl_xor(s, 2);
      s += __shfl_xor(s, 4);
      s += __shfl_xor(s, 8);
      if (l15 == 0) {
        int m = m0 + (wm << 7) + (rf << 4) + (quad << 2) + r;
        partials[m * 16 + (ntile << 2) + wn] = s;
      }
    }
  }
}

// ---- K2 m97-structure fallback (if 128K dyn-LDS attr refused) -------------
__global__ __launch_bounds__(256, 2) void k2_gemm_h(
    const _Float16* __restrict__ Ah, const _Float16* __restrict__ BT,
    const float* __restrict__ tq, const float* __restrict__ v,
    float* __restrict__ partials) {
  __shared__ _Float16 As[128 * 32];
  __shared__ _Float16 Bs[128 * 32];
  const int bid = blockIdx.x;
  const int mtile = ((bid >> 6) << 3) | (bid & 7);
  const int nblk = (bid >> 3) & 7;
  const int m0 = mtile << 7, n0 = nblk << 7;
  const int tid = threadIdx.x;
  const int w = tid >> 6, lane = tid & 63;
  const int wm = w >> 1, wn = w & 1, quad = lane >> 4, l15 = lane & 15;

  floatx4 acc[4][4];
  #pragma unroll
  for (int i = 0; i < 4; ++i)
    #pragma unroll
    for (int j = 0; j < 4; ++j) acc[i][j] = floatx4{0.f, 0.f, 0.f, 0.f};

  const _Float16 *gA[2], *gB[2];
  _Float16 *lA[2], *lB[2];
  #pragma unroll
  for (int t = 0; t < 2; ++t) {
    int L = (t << 8) + (w << 6) + lane;
    int row = L >> 2, jj = L & 3;
    int j = (jj - row - (row >> 2)) & 3;
    gA[t] = Ah + (size_t)(m0 + row) * 1024 + (j << 3);
    gB[t] = BT + (size_t)(n0 + row) * 1024 + (j << 3);
    lA[t] = As + (t << 11) + (w << 9);
    lB[t] = Bs + (t << 11) + (w << 9);
  }

  const half8_t *aaddr[4], *baddr[4];
  #pragma unroll
  for (int i = 0; i < 4; ++i) {
    int ar = (wm << 6) + (i << 4) + l15;
    aaddr[i] = (const half8_t*)(As + (ar << 5) + (((quad + ar + (ar >> 2)) & 3) << 3));
    int br = (wn << 6) + (i << 4) + l15;
    baddr[i] = (const half8_t*)(Bs + (br << 5) + (((quad + br + (br >> 2)) & 3) << 3));
  }

  for (int k0 = 0; k0 < 1024; k0 += 32) {
    __syncthreads();
    glds16(gA[0] + k0, lA[0]);
    glds16(gA[1] + k0, lA[1]);
    glds16(gB[0] + k0, lB[0]);
    glds16(gB[1] + k0, lB[1]);
    __syncthreads();
    half8_t af[4], bfr[4];
    #pragma unroll
    for (int i = 0; i < 4; ++i) af[i] = *aaddr[i];
    #pragma unroll
    for (int j = 0; j < 4; ++j) bfr[j] = *baddr[j];
    #pragma unroll
    for (int i = 0; i < 4; ++i)
      #pragma unroll
      for (int j = 0; j < 4; ++j)
        acc[i][j] = __builtin_amdgcn_mfma_f32_16x16x32_f16(af[i], bfr[j], acc[i][j], 0, 0, 0);
  }

  const int b = m0 >> 9;
  const int colbase = n0 + (wn << 6) + l15;
  float tqv[4], vv[4];
  #pragma unroll
  for (int j = 0; j < 4; ++j) {
    int n = colbase + (j << 4);
    tqv[j] = tq[(b << 10) + n];
    vv[j] = v[n];
  }
  #pragma unroll
  for (int i = 0; i < 4; ++i) {
    #pragma unroll
    for (int r = 0; r < 4; ++r) {
      float s = 0.f;
      #pragma unroll
      for (int j = 0; j < 4; ++j) s += fast_tanh(acc[i][j][r] + tqv[j]) * vv[j];
      s += __shfl_xor(s, 1);
      s += __shfl_xor(s, 2);
      s += __shfl_xor(s, 4);
      s += __shfl_xor(s, 8);
      if (l15 == 0) {
        int m = m0 + (wm << 6) + (i << 4) + (quad << 2) + r;
        partials[m * 16 + (nblk << 1) + wn] = s;
      }
    }
  }
}

// ---- K2 fallback (fp32 A staging) — small-ws verified path ----------------
__global__ __launch_bounds__(256, 2) void k2_gemm_f32(
    const float* __restrict__ A, const _Float16* __restrict__ BT,
    const float* __restrict__ tq, const float* __restrict__ v,
    float* __restrict__ partials) {
  __shared__ float As[128 * 32];
  __shared__ _Float16 Bs[128 * 32];
  const int bid = blockIdx.x;
  const int mtile = ((bid >> 6) << 3) | (bid & 7);
  const int nblk = (bid >> 3) & 7;
  const int m0 = mtile << 7, n0 = nblk << 7;
  const int tid = threadIdx.x;
  const int w = tid >> 6, lane = tid & 63;
  const int wm = w >> 1, wn = w & 1, quad = lane >> 4, l15 = lane & 15;

  floatx4 acc[4][4];
  #pragma unroll
  for (int i = 0; i < 4; ++i)
    #pragma unroll
    for (int j = 0; j < 4; ++j) acc[i][j] = floatx4{0.f, 0.f, 0.f, 0.f};

  const float* gA[4];
  float* lA[4];
  #pragma unroll
  for (int t = 0; t < 4; ++t) {
    int L = (t << 8) + (w << 6) + lane;
    int row = L >> 3, jj = L & 7;
    int j = (jj - row) & 7;
    gA[t] = A + (size_t)(m0 + row) * 1024 + (j << 2);
    lA[t] = As + (t << 10) + (w << 8);
  }
  const _Float16* gB[2];
  _Float16* lB[2];
  #pragma unroll
  for (int t = 0; t < 2; ++t) {
    int L = (t << 8) + (w << 6) + lane;
    int row = L >> 2, jj = L & 3;
    int j = (jj - row - (row >> 2)) & 3;
    gB[t] = BT + (size_t)(n0 + row) * 1024 + (j << 3);
    lB[t] = Bs + (t << 11) + (w << 9);
  }
  const floatx4* aaddr[4][2];
  #pragma unroll
  for (int i = 0; i < 4; ++i) {
    int row = (wm << 6) + (i << 4) + l15;
    #pragma unroll
    for (int h = 0; h < 2; ++h) {
      int pos = ((quad << 1) + h + row) & 7;
      aaddr[i][h] = (const floatx4*)(As + (row << 5) + (pos << 2));
    }
  }
  const half8_t* baddr[4];
  #pragma unroll
  for (int j = 0; j < 4; ++j) {
    int row = (wn << 6) + (j << 4) + l15;
    int pos = (quad + row + (row >> 2)) & 3;
    baddr[j] = (const half8_t*)(Bs + (row << 5) + (pos << 3));
  }
  for (int k0 = 0; k0 < 1024; k0 += 32) {
    __syncthreads();
    glds16(gA[0] + k0, lA[0]);
    glds16(gA[1] + k0, lA[1]);
    glds16(gA[2] + k0, lA[2]);
    glds16(gA[3] + k0, lA[3]);
    glds16(gB[0] + k0, lB[0]);
    glds16(gB[1] + k0, lB[1]);
    __syncthreads();
    half8_t af[4], bfr[4];
    #pragma unroll
    for (int i = 0; i < 4; ++i) {
      floatx4 x = *aaddr[i][0], y = *aaddr[i][1];
      union { half2_t h2[4]; half8_t h8; } u;
      u.h2[0] = pkrtz(x[0], x[1]);
      u.h2[1] = pkrtz(x[2], x[3]);
      u.h2[2] = pkrtz(y[0], y[1]);
      u.h2[3] = pkrtz(y[2], y[3]);
      af[i] = u.h8;
    }
    #pragma unroll
    for (int j = 0; j < 4; ++j) bfr[j] = *baddr[j];
    #pragma unroll
    for (int i = 0; i < 4; ++i)
      #pragma unroll
      for (int j = 0; j < 4; ++j)
        acc[i][j] = __builtin_amdgcn_mfma_f32_16x16x32_f16(af[i], bfr[j], acc[i][j], 0, 0, 0);
  }
  const int b = m0 >> 9;
  const int colbase = n0 + (wn << 6) + l15;
  float tqv[4], vv[4];
  #pragma unroll
  for (int j = 0; j < 4; ++j) {
    int n = colbase + (j << 4);
    tqv[j] = tq[(b << 10) + n];
    vv[j] = v[n];
  }
  #pragma unroll
  for (int i = 0; i < 4; ++i) {
    #pragma unroll
    for (int r = 0; r < 4; ++r) {
      float s = 0.f;
      #pragma unroll
      for (int j = 0; j < 4; ++j) s += fast_tanh(acc[i][j][r] + tqv[j]) * vv[j];
      s += __shfl_xor(s, 1);
      s += __shfl_xor(s, 2);
      s += __shfl_xor(s, 4);
      s += __shfl_xor(s, 8);
      if (l15 == 0) {
        int m = m0 + (wm << 6) + (i << 4) + (quad << 2) + r;
        partials[m * 16 + (nblk << 1) + wn] = s;
      }
    }
  }
}

// ---- K3: masked softmax over N=512 per batch ------------------------------
__global__ __launch_bounds__(512) void k3_softmax(const float* __restrict__ partials,
                                                  const int* __restrict__ mask,
                                                  float* __restrict__ weights) {
  int b = blockIdx.x;
  int n = threadIdx.x;
  int m = (b << 9) + n;
  float s = 0.f;
  #pragma unroll
  for (int i = 0; i < 16; ++i) s += partials[m * 16 + i];
  int mk = mask[m];
  float logit = mk ? s : -1e30f;
  __shared__ float red[8];
  float x = logit;
  #pragma unroll
  for (int off = 32; off > 0; off >>= 1) x = fmaxf(x, __shfl_xor(x, off));
  if ((n & 63) == 0) red[n >> 6] = x;
  __syncthreads();
  float mx = red[0];
  #pragma unroll
  for (int i = 1; i < 8; ++i) mx = fmaxf(mx, red[i]);
  float e = mk ? __expf(logit - mx) : 0.f;
  float ss = e;
  #pragma unroll
  for (int off = 32; off > 0; off >>= 1) ss += __shfl_xor(ss, off);
  __syncthreads();
  if ((n & 63) == 0) red[n >> 6] = ss;
  __syncthreads();
  float tot = 0.f;
  #pragma unroll
  for (int i = 0; i < 8; ++i) tot += red[i];
  weights[m] = (tot > 0.f) ? e / tot : 0.f;
}

// ---- K4 (fp16 mem): context partials over 32-row chunks, grid (16,64) -----
__global__ void k4_ctx_h(const _Float16* __restrict__ memh,
                         const float* __restrict__ weights, float* __restrict__ ctxp) {
  int nc = blockIdx.x, b = blockIdx.y;
  int d = threadIdx.x << 3;
  float acc[8] = {0.f, 0.f, 0.f, 0.f, 0.f, 0.f, 0.f, 0.f};
  int nbase = nc << 5;
  for (int n = nbase; n < nbase + 32; ++n) {
    float wv = weights[(b << 9) + n];
    half8_t x = *(const half8_t*)(memh + ((size_t)((b << 9) + n) << 10) + d);
    #pragma unroll
    for (int k = 0; k < 8; ++k) acc[k] += wv * (float)x[k];
  }
  float* o = ctxp + ((size_t)((b << 4) + nc) << 10) + d;
  #pragma unroll
  for (int k = 0; k < 8; ++k) o[k] = acc[k];
}

__global__ void k5_reduce16(const float* __restrict__ ctxp, float* __restrict__ out) {
  int i = (blockIdx.x << 8) + threadIdx.x;
  int b = i >> 10, d = i & 1023;
  float s = 0.f;
  #pragma unroll
  for (int cc = 0; cc < 16; ++cc) s += ctxp[((size_t)((b << 4) + cc) << 10) + d];
  out[i] = s;
}

// ---- fp32-path K4/K5 ------------------------------------------------------
__global__ void k4_ctx_f32(const float* __restrict__ mem, const float* __restrict__ weights,
                           float* __restrict__ ctxp) {
  int nc = blockIdx.x, b = blockIdx.y;
  int d = threadIdx.x << 3;
  floatx4 a0 = {0.f, 0.f, 0.f, 0.f}, a1 = {0.f, 0.f, 0.f, 0.f};
  int nbase = nc << 6;
  for (int n = nbase; n < nbase + 64; ++n) {
    float wv = weights[(b << 9) + n];
    const floatx4* p = (const floatx4*)(mem + ((size_t)((b << 9) + n) << 10) + d);
    a0 += wv * p[0];
    a1 += wv * p[1];
  }
  floatx4* o = (floatx4*)(ctxp + ((size_t)((b << 3) + nc) << 10) + d);
  o[0] = a0;
  o[1] = a1;
}

__global__ void k5_reduce8(const float* __restrict__ ctxp, float* __restrict__ out) {
  int i = (blockIdx.x << 8) + threadIdx.x;
  int b = i >> 10, d = i & 1023;
  float s = 0.f;
  #pragma unroll
  for (int cc = 0; cc < 8; ++cc) s += ctxp[((size_t)((b << 3) + cc) << 10) + d];
  out[i] = s;
}

extern "C" void kernel_launch(void* const* d_in, const int* in_sizes, int n_in,
                              void* d_out, int out_size, void* d_ws, size_t ws_size,
                              hipStream_t stream) {
  const float* mem = (const float*)d_in[0];   // (64,512,1024) fp32
  const int* mask = (const int*)d_in[1];      // (64,512) int32
  const float* query = (const float*)d_in[2]; // (64,1024) fp32
  const float* Wh = (const float*)d_in[3];    // (1024,1024) fp32
  const float* Ws = (const float*)d_in[4];    // (1024,1024) fp32
  const float* v = (const float*)d_in[5];     // (1024,1) fp32
  float* out = (float*)d_out;                 // (64,1024) fp32

  char* ws = (char*)d_ws;
  const size_t need16 = (73ull << 20);

  if (ws_size >= need16) {
    _Float16* memh = (_Float16*)ws;                                    // 64 MiB
    _Float16* WhT = (_Float16*)(ws + (64ull << 20));                   // 2 MiB
    float* partials = (float*)(ws + (66ull << 20));                    // 2 MiB
    float* tq = (float*)(ws + (68ull << 20));                          // 256 KiB
    float* weights = (float*)(ws + (68ull << 20) + (256 << 10));       // 128 KiB
    float* ctxp = (float*)(ws + (69ull << 20));                        // 4 MiB

    static int use8 = -1;
    if (use8 < 0) {
      use8 = (hipFuncSetAttribute((const void*)k2_8ph,
                                  hipFuncAttributeMaxDynamicSharedMemorySize,
                                  131072) == hipSuccess) ? 1 : 0;
    }

    k_prep<<<17664, 256, 0, stream>>>(mem, memh, Wh, WhT, query, Ws, tq);
    if (use8)
      k2_8ph<<<512, 512, 131072, stream>>>(memh, WhT, tq, v, partials);
    else
      k2_gemm_h<<<2048, 256, 0, stream>>>(memh, WhT, tq, v, partials);
    k3_softmax<<<64, 512, 0, stream>>>(partials, mask, weights);
    k4_ctx_h<<<dim3(16, 64), 128, 0, stream>>>(memh, weights, ctxp);
    k5_reduce16<<<256, 256, 0, stream>>>(ctxp, out);
  } else {
    _Float16* WhT = (_Float16*)ws;                                     // 2 MiB
    float* partials = (float*)(ws + ((size_t)2 << 20));                // 2 MiB
    float* tq = (float*)(ws + ((size_t)4 << 20));                      // 256 KiB
    float* weights = (float*)(ws + ((size_t)4 << 20) + (256 << 10));   // 128 KiB
    float* ctxp = (float*)(ws + ((size_t)9 << 19));                    // 2 MiB

    k0_transpose<<<dim3(16, 16), dim3(64, 4), 0, stream>>>(Wh, WhT);
    k1_tq<<<dim3(16, 64), 256, 0, stream>>>(query, Ws, tq);
    k2_gemm_f32<<<2048, 256, 0, stream>>>(mem, WhT, tq, v, partials);
    k3_softmax<<<64, 512, 0, stream>>>(partials, mask, weights);
    k4_ctx_f32<<<dim3(8, 64), 128, 0, stream>>>(mem, weights, ctxp);
    k5_reduce8<<<256, 256, 0, stream>>>(ctxp, out);
  }
}

// Round 3
// 301.081 us; speedup vs baseline: 1.0338x; 1.0338x over previous
//
#include <hip/hip_runtime.h>
#include <cstdint>
#include <cstddef>

typedef float floatx4 __attribute__((ext_vector_type(4)));
typedef _Float16 half8_t __attribute__((ext_vector_type(8)));
typedef _Float16 half2_t __attribute__((ext_vector_type(2)));

#define AS1 __attribute__((address_space(1)))
#define AS3 __attribute__((address_space(3)))

__device__ __forceinline__ void glds16(const void* g, void* l) {
  __builtin_amdgcn_global_load_lds((const AS1 void*)g, (AS3 void*)l, 16, 0, 0);
}

__device__ __forceinline__ half2_t pkrtz(float a, float b) {
  return __builtin_bit_cast(half2_t, __builtin_amdgcn_cvt_pkrtz(a, b));
}

__device__ __forceinline__ float fast_tanh(float x) {
  // tanh(x) = 1 - 2/(e^{2x}+1); inf-safe (e2=inf -> rcp=0 -> 1; e2=0 -> -1)
  float e2 = __expf(2.f * x);
  return 1.f - 2.f * __builtin_amdgcn_rcpf(e2 + 1.f);
}

// ---- k_prep: fused {Wh transpose->f16 | tq = q@Ws | memf32->f16 cvt} ------
// Long-latency small-grid work FIRST so it overlaps the cvt stream:
// blocks [0,256): transpose ; [256,1280): tq ; [1280,17664): cvt
__global__ __launch_bounds__(256) void k_prep(
    const float* __restrict__ mem, _Float16* __restrict__ memh,
    const float* __restrict__ Wh, _Float16* __restrict__ WhT,
    const float* __restrict__ q, const float* __restrict__ Ws,
    float* __restrict__ tq) {
  __shared__ float sh[64 * 65];
  const int bx = blockIdx.x;
  const int tid = threadIdx.x;
  if (bx >= 1280) {
    size_t i = (((size_t)(bx - 1280) << 8) + tid) << 3;
    floatx4 a = *(const floatx4*)(mem + i);
    floatx4 b = *(const floatx4*)(mem + i + 4);
    union { half2_t h2[4]; half8_t h8; } u;
    u.h2[0] = half2_t{(_Float16)a[0], (_Float16)a[1]};
    u.h2[1] = half2_t{(_Float16)a[2], (_Float16)a[3]};
    u.h2[2] = half2_t{(_Float16)b[0], (_Float16)b[1]};
    u.h2[3] = half2_t{(_Float16)b[2], (_Float16)b[3]};
    *(half8_t*)(memh + i) = u.h8;
  } else if (bx < 256) {
    int bb = bx;
    int n0 = (bb & 15) << 6, k0 = (bb >> 4) << 6;
    int tx = tid & 63, ty = tid >> 6;
    #pragma unroll
    for (int r = ty; r < 64; r += 4) sh[r * 65 + tx] = Wh[(size_t)(k0 + r) * 1024 + n0 + tx];
    __syncthreads();
    #pragma unroll
    for (int r = ty; r < 64; r += 4)
      WhT[(size_t)(n0 + r) * 1024 + k0 + tx] = (_Float16)sh[tx * 65 + r];
  } else {
    int bb = bx - 256;
    int d0 = (bb & 15) << 6, b = bb >> 4;
    int dl = tid & 63, kg = tid >> 6;
    float* qs = sh;
    float* red = sh + 1024;  // [4][64]
    for (int k = tid; k < 1024; k += 256) qs[k] = q[(b << 10) + k];
    __syncthreads();
    float acc = 0.f;
    int kbase = kg << 8;
    #pragma unroll 8
    for (int k = 0; k < 256; ++k)
      acc += qs[kbase + k] * Ws[(size_t)(kbase + k) * 1024 + d0 + dl];
    red[(kg << 6) + dl] = acc;
    __syncthreads();
    if (kg == 0)
      tq[(b << 10) + d0 + dl] = red[dl] + red[64 + dl] + red[128 + dl] + red[192 + dl];
  }
}

// ---- K0/K1 standalone (small-ws fallback path) ----------------------------
__global__ void k0_transpose(const float* __restrict__ Wh, _Float16* __restrict__ WhT) {
  __shared__ float t[64][65];
  int k0 = blockIdx.y << 6, n0 = blockIdx.x << 6;
  int tx = threadIdx.x, ty = threadIdx.y;
  #pragma unroll
  for (int r = ty; r < 64; r += 4) t[r][tx] = Wh[(size_t)(k0 + r) * 1024 + n0 + tx];
  __syncthreads();
  #pragma unroll
  for (int r = ty; r < 64; r += 4)
    WhT[(size_t)(n0 + r) * 1024 + k0 + tx] = (_Float16)t[tx][r];
}

__global__ __launch_bounds__(256) void k1_tq(const float* __restrict__ q,
                                             const float* __restrict__ Ws,
                                             float* __restrict__ tq) {
  __shared__ float qs[1024];
  __shared__ float red[4][64];
  int b = blockIdx.y;
  int d0 = blockIdx.x << 6;
  int dl = threadIdx.x & 63, kg = threadIdx.x >> 6;
  for (int k = threadIdx.x; k < 1024; k += 256) qs[k] = q[(b << 10) + k];
  __syncthreads();
  float acc = 0.f;
  int kbase = kg << 8;
  #pragma unroll 8
  for (int k = 0; k < 256; ++k)
    acc += qs[kbase + k] * Ws[(size_t)(kbase + k) * 1024 + d0 + dl];
  red[kg][dl] = acc;
  __syncthreads();
  if (kg == 0)
    tq[(b << 10) + d0 + dl] = red[0][dl] + red[1][dl] + red[2][dl] + red[3][dl];
}

// ---- K2 deep-pipe: 256x256 tile, BK=64, 8 waves, 1-vmcnt/2-barrier group --
// A = memh (32768x1024 f16), BT = WhT (1024x1024 f16 n-major).
// LDS (128 KiB dynamic):
//   A: buf*32768 + (wm*2+rh)*8192 + r6*128 + chunk*16        (r6 in [0,64))
//   B: 65536 + buf*32768 + ch*16384 + wn*4096 + r5*128 + c*16
// Swizzle: chunk_stored = chunk_logical ^ (row & 7) via inverse-swz global
// source (glds dest stays linear); swz applied on the ds_read side.
// Group T: issue ALL 8 stages for tile T+1 into buf[cur^1], then vmcnt(8)
// (waits only tile T's loads, issued one full group ~2048cy earlier ->
// latency covered), one barrier, 64 uninterrupted MFMA (compiler schedules
// ds_read/lgkmcnt interleave), closing barrier (protects buf[cur] from
// group T+1's stages). 2 barriers + 1 counted vmcnt per K-tile.
__global__ __launch_bounds__(512, 2) void k2_8ph(
    const _Float16* __restrict__ Ah, const _Float16* __restrict__ BT,
    const float* __restrict__ tq, const float* __restrict__ v,
    float* __restrict__ partials) {
  extern __shared__ char smem[];
  const int bid = blockIdx.x;
  const int wg = ((bid & 7) << 6) | (bid >> 3);  // bijective XCD swizzle (512 wgs)
  const int mtile = wg >> 2, ntile = wg & 3;
  const int m0 = mtile << 8, n0 = ntile << 8;
  const int tid = threadIdx.x;
  const int w = tid >> 6, lane = tid & 63;
  const int wm = w >> 2, wn = w & 3, quad = lane >> 4, l15 = lane & 15;

  // ds_read byte offsets (sans buf/rh/ch bases)
  int aoff[2][4], boff[2][2];
  #pragma unroll
  for (int ks = 0; ks < 2; ++ks) {
    int swz = ((ks << 2) + quad) ^ (l15 & 7);
    #pragma unroll
    for (int i = 0; i < 4; ++i)
      aoff[ks][i] = (wm << 14) + (((i << 4) + l15) << 7) + (swz << 4);
    #pragma unroll
    for (int j = 0; j < 2; ++j)
      boff[ks][j] = 65536 + (wn << 12) + (((j << 4) + l15) << 7) + (swz << 4);
  }

  // staging: per-thread global src offsets (f16 elems) + wave-uniform LDS dst
  const int rr = tid >> 3, cc = tid & 7;
  const int r5 = rr & 31;
  int aSrc[2][2], bSrc[2][2], dA[2][2], dB[2][2];
  #pragma unroll
  for (int h = 0; h < 2; ++h)
    #pragma unroll
    for (int hm = 0; hm < 2; ++hm) {
      aSrc[h][hm] = ((m0 + (hm << 7) + (h << 6) + rr) << 10) + ((cc ^ (rr & 7)) << 3);
      dA[h][hm] = (((hm << 1) + h) << 13) + (w << 10);
    }
  #pragma unroll
  for (int ch = 0; ch < 2; ++ch)
    #pragma unroll
    for (int is = 0; is < 2; ++is) {
      int wnb = (is << 1) + (rr >> 5);
      bSrc[ch][is] = ((n0 + (wnb << 6) + (ch << 5) + r5) << 10) + ((cc ^ (r5 & 7)) << 3);
      dB[ch][is] = 65536 + (ch << 14) + (is << 13) + (w << 10);
    }

  floatx4 acc[8][4];
  #pragma unroll
  for (int i = 0; i < 8; ++i)
    #pragma unroll
    for (int j = 0; j < 4; ++j) acc[i][j] = floatx4{0.f, 0.f, 0.f, 0.f};

  half8_t af[2][4], bf[2][2][2];

#define STAGE_A(H, KST, OO)                                   \
  glds16(Ah + aSrc[H][0] + (KST), smem + (OO) + dA[H][0]);    \
  glds16(Ah + aSrc[H][1] + (KST), smem + (OO) + dA[H][1]);
#define STAGE_B(CH, KST, OO)                                  \
  glds16(BT + bSrc[CH][0] + (KST), smem + (OO) + dB[CH][0]);  \
  glds16(BT + bSrc[CH][1] + (KST), smem + (OO) + dB[CH][1]);
#define VMCNT8 asm volatile("s_waitcnt vmcnt(8)" ::: "memory");
#define LOAD_AF(CO, RHOFF)                                    \
  _Pragma("unroll")                                           \
  for (int ks_ = 0; ks_ < 2; ++ks_) {                         \
    _Pragma("unroll")                                         \
    for (int i_ = 0; i_ < 4; ++i_)                            \
      af[ks_][i_] = *(const half8_t*)(smem + (CO) + (RHOFF) + aoff[ks_][i_]); \
  }
#define LOAD_BF(CH, CO, CHOFF)                                \
  _Pragma("unroll")                                           \
  for (int ks_ = 0; ks_ < 2; ++ks_) {                         \
    _Pragma("unroll")                                         \
    for (int j_ = 0; j_ < 2; ++j_)                            \
      bf[CH][ks_][j_] = *(const half8_t*)(smem + (CO) + (CHOFF) + boff[ks_][j_]); \
  }
#define MFMAS(RH, CH)                                         \
  _Pragma("unroll")                                           \
  for (int ks_ = 0; ks_ < 2; ++ks_) {                         \
    _Pragma("unroll")                                         \
    for (int i_ = 0; i_ < 4; ++i_) {                          \
      _Pragma("unroll")                                       \
      for (int j_ = 0; j_ < 2; ++j_)                          \
        acc[(RH)*4 + i_][(CH)*2 + j_] = __builtin_amdgcn_mfma_f32_16x16x32_f16( \
            af[ks_][i_], bf[CH][ks_][j_], acc[(RH)*4 + i_][(CH)*2 + j_], 0, 0, 0); \
    }                                                         \
  }
#define GROUPN(CO, OO, KST)                                   \
  STAGE_A(0, KST, OO)                                         \
  STAGE_B(0, KST, OO)                                         \
  STAGE_B(1, KST, OO)                                         \
  STAGE_A(1, KST, OO)                                         \
  VMCNT8                                                      \
  __builtin_amdgcn_s_barrier();                               \
  asm volatile("" ::: "memory");                              \
  __builtin_amdgcn_s_setprio(1);                              \
  LOAD_AF(CO, 0)                                              \
  LOAD_BF(0, CO, 0)                                           \
  MFMAS(0, 0)                                                 \
  LOAD_BF(1, CO, 16384)                                       \
  MFMAS(0, 1)                                                 \
  LOAD_AF(CO, 8192)                                           \
  MFMAS(1, 0)                                                 \
  MFMAS(1, 1)                                                 \
  __builtin_amdgcn_s_setprio(0);                              \
  asm volatile("" ::: "memory");                              \
  __builtin_amdgcn_s_barrier();

  // prologue: stage tile 0 -> buf0 (no wait; group 0's vmcnt(8) covers it)
  STAGE_A(0, 0, 0)
  STAGE_B(0, 0, 0)
  STAGE_B(1, 0, 0)
  STAGE_A(1, 0, 0)

  #pragma unroll 1
  for (int g2 = 0; g2 < 8; ++g2) {
    const int g = g2 << 1;
    const int kst1 = (g + 1) << 6;
    const int kst2 = (g2 == 7) ? (15 << 6) : ((g + 2) << 6);  // clamp: redundant last stage keeps ledger uniform
    GROUPN(0, 32768, kst1)
    GROUPN(32768, 0, kst2)
  }

#undef GROUPN
#undef MFMAS
#undef LOAD_BF
#undef LOAD_AF
#undef VMCNT8
#undef STAGE_B
#undef STAGE_A

  // drain in-flight DMA before the block can exit / LDS reuse
  asm volatile("s_waitcnt vmcnt(0)" ::: "memory");

  // epilogue: tanh(acc + tq) . v, reduce across 16 lanes, write partials
  const int b = m0 >> 9;
  const int colb = n0 + (wn << 6) + l15;
  float tqv[4], vv[4];
  #pragma unroll
  for (int jf = 0; jf < 4; ++jf) {
    int n = colb + (jf << 4);
    tqv[jf] = tq[(b << 10) + n];
    vv[jf] = v[n];
  }
  #pragma unroll
  for (int rf = 0; rf < 8; ++rf) {
    #pragma unroll
    for (int r = 0; r < 4; ++r) {
      float s = 0.f;
      #pragma unroll
      for (int jf = 0; jf < 4; ++jf) s += fast_tanh(acc[rf][jf][r] + tqv[jf]) * vv[jf];
      s += __shfl_xor(s, 1);
      s += __shfl_xor(s, 2);
      s += __shfl_xor(s, 4);
      s += __shfl_xor(s, 8);
      if (l15 == 0) {
        int m = m0 + (wm << 7) + (rf << 4) + (quad << 2) + r;
        partials[m * 16 + (ntile << 2) + wn] = s;
      }
    }
  }
}

// ---- K2 m97-structure fallback (if 128K dyn-LDS attr refused) -------------
__global__ __launch_bounds__(256, 2) void k2_gemm_h(
    const _Float16* __restrict__ Ah, const _Float16* __restrict__ BT,
    const float* __restrict__ tq, const float* __restrict__ v,
    float* __restrict__ partials) {
  __shared__ _Float16 As[128 * 32];
  __shared__ _Float16 Bs[128 * 32];
  const int bid = blockIdx.x;
  const int mtile = ((bid >> 6) << 3) | (bid & 7);
  const int nblk = (bid >> 3) & 7;
  const int m0 = mtile << 7, n0 = nblk << 7;
  const int tid = threadIdx.x;
  const int w = tid >> 6, lane = tid & 63;
  const int wm = w >> 1, wn = w & 1, quad = lane >> 4, l15 = lane & 15;

  floatx4 acc[4][4];
  #pragma unroll
  for (int i = 0; i < 4; ++i)
    #pragma unroll
    for (int j = 0; j < 4; ++j) acc[i][j] = floatx4{0.f, 0.f, 0.f, 0.f};

  const _Float16 *gA[2], *gB[2];
  _Float16 *lA[2], *lB[2];
  #pragma unroll
  for (int t = 0; t < 2; ++t) {
    int L = (t << 8) + (w << 6) + lane;
    int row = L >> 2, jj = L & 3;
    int j = (jj - row - (row >> 2)) & 3;
    gA[t] = Ah + (size_t)(m0 + row) * 1024 + (j << 3);
    gB[t] = BT + (size_t)(n0 + row) * 1024 + (j << 3);
    lA[t] = As + (t << 11) + (w << 9);
    lB[t] = Bs + (t << 11) + (w << 9);
  }

  const half8_t *aaddr[4], *baddr[4];
  #pragma unroll
  for (int i = 0; i < 4; ++i) {
    int ar = (wm << 6) + (i << 4) + l15;
    aaddr[i] = (const half8_t*)(As + (ar << 5) + (((quad + ar + (ar >> 2)) & 3) << 3));
    int br = (wn << 6) + (i << 4) + l15;
    baddr[i] = (const half8_t*)(Bs + (br << 5) + (((quad + br + (br >> 2)) & 3) << 3));
  }

  for (int k0 = 0; k0 < 1024; k0 += 32) {
    __syncthreads();
    glds16(gA[0] + k0, lA[0]);
    glds16(gA[1] + k0, lA[1]);
    glds16(gB[0] + k0, lB[0]);
    glds16(gB[1] + k0, lB[1]);
    __syncthreads();
    half8_t af[4], bfr[4];
    #pragma unroll
    for (int i = 0; i < 4; ++i) af[i] = *aaddr[i];
    #pragma unroll
    for (int j = 0; j < 4; ++j) bfr[j] = *baddr[j];
    #pragma unroll
    for (int i = 0; i < 4; ++i)
      #pragma unroll
      for (int j = 0; j < 4; ++j)
        acc[i][j] = __builtin_amdgcn_mfma_f32_16x16x32_f16(af[i], bfr[j], acc[i][j], 0, 0, 0);
  }

  const int b = m0 >> 9;
  const int colbase = n0 + (wn << 6) + l15;
  float tqv[4], vv[4];
  #pragma unroll
  for (int j = 0; j < 4; ++j) {
    int n = colbase + (j << 4);
    tqv[j] = tq[(b << 10) + n];
    vv[j] = v[n];
  }
  #pragma unroll
  for (int i = 0; i < 4; ++i) {
    #pragma unroll
    for (int r = 0; r < 4; ++r) {
      float s = 0.f;
      #pragma unroll
      for (int j = 0; j < 4; ++j) s += fast_tanh(acc[i][j][r] + tqv[j]) * vv[j];
      s += __shfl_xor(s, 1);
      s += __shfl_xor(s, 2);
      s += __shfl_xor(s, 4);
      s += __shfl_xor(s, 8);
      if (l15 == 0) {
        int m = m0 + (wm << 6) + (i << 4) + (quad << 2) + r;
        partials[m * 16 + (nblk << 1) + wn] = s;
      }
    }
  }
}

// ---- K2 fallback (fp32 A staging) — small-ws verified path ----------------
__global__ __launch_bounds__(256, 2) void k2_gemm_f32(
    const float* __restrict__ A, const _Float16* __restrict__ BT,
    const float* __restrict__ tq, const float* __restrict__ v,
    float* __restrict__ partials) {
  __shared__ float As[128 * 32];
  __shared__ _Float16 Bs[128 * 32];
  const int bid = blockIdx.x;
  const int mtile = ((bid >> 6) << 3) | (bid & 7);
  const int nblk = (bid >> 3) & 7;
  const int m0 = mtile << 7, n0 = nblk << 7;
  const int tid = threadIdx.x;
  const int w = tid >> 6, lane = tid & 63;
  const int wm = w >> 1, wn = w & 1, quad = lane >> 4, l15 = lane & 15;

  floatx4 acc[4][4];
  #pragma unroll
  for (int i = 0; i < 4; ++i)
    #pragma unroll
    for (int j = 0; j < 4; ++j) acc[i][j] = floatx4{0.f, 0.f, 0.f, 0.f};

  const float* gA[4];
  float* lA[4];
  #pragma unroll
  for (int t = 0; t < 4; ++t) {
    int L = (t << 8) + (w << 6) + lane;
    int row = L >> 3, jj = L & 7;
    int j = (jj - row) & 7;
    gA[t] = A + (size_t)(m0 + row) * 1024 + (j << 2);
    lA[t] = As + (t << 10) + (w << 8);
  }
  const _Float16* gB[2];
  _Float16* lB[2];
  #pragma unroll
  for (int t = 0; t < 2; ++t) {
    int L = (t << 8) + (w << 6) + lane;
    int row = L >> 2, jj = L & 3;
    int j = (jj - row - (row >> 2)) & 3;
    gB[t] = BT + (size_t)(n0 + row) * 1024 + (j << 3);
    lB[t] = Bs + (t << 11) + (w << 9);
  }
  const floatx4* aaddr[4][2];
  #pragma unroll
  for (int i = 0; i < 4; ++i) {
    int row = (wm << 6) + (i << 4) + l15;
    #pragma unroll
    for (int h = 0; h < 2; ++h) {
      int pos = ((quad << 1) + h + row) & 7;
      aaddr[i][h] = (const floatx4*)(As + (row << 5) + (pos << 2));
    }
  }
  const half8_t* baddr[4];
  #pragma unroll
  for (int j = 0; j < 4; ++j) {
    int row = (wn << 6) + (j << 4) + l15;
    int pos = (quad + row + (row >> 2)) & 3;
    baddr[j] = (const half8_t*)(Bs + (row << 5) + (pos << 3));
  }
  for (int k0 = 0; k0 < 1024; k0 += 32) {
    __syncthreads();
    glds16(gA[0] + k0, lA[0]);
    glds16(gA[1] + k0, lA[1]);
    glds16(gA[2] + k0, lA[2]);
    glds16(gA[3] + k0, lA[3]);
    glds16(gB[0] + k0, lB[0]);
    glds16(gB[1] + k0, lB[1]);
    __syncthreads();
    half8_t af[4], bfr[4];
    #pragma unroll
    for (int i = 0; i < 4; ++i) {
      floatx4 x = *aaddr[i][0], y = *aaddr[i][1];
      union { half2_t h2[4]; half8_t h8; } u;
      u.h2[0] = pkrtz(x[0], x[1]);
      u.h2[1] = pkrtz(x[2], x[3]);
      u.h2[2] = pkrtz(y[0], y[1]);
      u.h2[3] = pkrtz(y[2], y[3]);
      af[i] = u.h8;
    }
    #pragma unroll
    for (int j = 0; j < 4; ++j) bfr[j] = *baddr[j];
    #pragma unroll
    for (int i = 0; i < 4; ++i)
      #pragma unroll
      for (int j = 0; j < 4; ++j)
        acc[i][j] = __builtin_amdgcn_mfma_f32_16x16x32_f16(af[i], bfr[j], acc[i][j], 0, 0, 0);
  }
  const int b = m0 >> 9;
  const int colbase = n0 + (wn << 6) + l15;
  float tqv[4], vv[4];
  #pragma unroll
  for (int j = 0; j < 4; ++j) {
    int n = colbase + (j << 4);
    tqv[j] = tq[(b << 10) + n];
    vv[j] = v[n];
  }
  #pragma unroll
  for (int i = 0; i < 4; ++i) {
    #pragma unroll
    for (int r = 0; r < 4; ++r) {
      float s = 0.f;
      #pragma unroll
      for (int j = 0; j < 4; ++j) s += fast_tanh(acc[i][j][r] + tqv[j]) * vv[j];
      s += __shfl_xor(s, 1);
      s += __shfl_xor(s, 2);
      s += __shfl_xor(s, 4);
      s += __shfl_xor(s, 8);
      if (l15 == 0) {
        int m = m0 + (wm << 6) + (i << 4) + (quad << 2) + r;
        partials[m * 16 + (nblk << 1) + wn] = s;
      }
    }
  }
}

// ---- K3: masked softmax over N=512 per batch ------------------------------
__global__ __launch_bounds__(512) void k3_softmax(const float* __restrict__ partials,
                                                  const int* __restrict__ mask,
                                                  float* __restrict__ weights) {
  int b = blockIdx.x;
  int n = threadIdx.x;
  int m = (b << 9) + n;
  float s = 0.f;
  #pragma unroll
  for (int i = 0; i < 16; ++i) s += partials[m * 16 + i];
  int mk = mask[m];
  float logit = mk ? s : -1e30f;
  __shared__ float red[8];
  float x = logit;
  #pragma unroll
  for (int off = 32; off > 0; off >>= 1) x = fmaxf(x, __shfl_xor(x, off));
  if ((n & 63) == 0) red[n >> 6] = x;
  __syncthreads();
  float mx = red[0];
  #pragma unroll
  for (int i = 1; i < 8; ++i) mx = fmaxf(mx, red[i]);
  float e = mk ? __expf(logit - mx) : 0.f;
  float ss = e;
  #pragma unroll
  for (int off = 32; off > 0; off >>= 1) ss += __shfl_xor(ss, off);
  __syncthreads();
  if ((n & 63) == 0) red[n >> 6] = ss;
  __syncthreads();
  float tot = 0.f;
  #pragma unroll
  for (int i = 0; i < 8; ++i) tot += red[i];
  weights[m] = (tot > 0.f) ? e / tot : 0.f;
}

// ---- K4 (fp16 mem): context partials over 32-row chunks, grid (16,64) -----
__global__ void k4_ctx_h(const _Float16* __restrict__ memh,
                         const float* __restrict__ weights, float* __restrict__ ctxp) {
  int nc = blockIdx.x, b = blockIdx.y;
  int d = threadIdx.x << 3;
  float acc[8] = {0.f, 0.f, 0.f, 0.f, 0.f, 0.f, 0.f, 0.f};
  int nbase = nc << 5;
  for (int n = nbase; n < nbase + 32; ++n) {
    float wv = weights[(b << 9) + n];
    half8_t x = *(const half8_t*)(memh + ((size_t)((b << 9) + n) << 10) + d);
    #pragma unroll
    for (int k = 0; k < 8; ++k) acc[k] += wv * (float)x[k];
  }
  float* o = ctxp + ((size_t)((b << 4) + nc) << 10) + d;
  #pragma unroll
  for (int k = 0; k < 8; ++k) o[k] = acc[k];
}

__global__ void k5_reduce16(const float* __restrict__ ctxp, float* __restrict__ out) {
  int i = (blockIdx.x << 8) + threadIdx.x;
  int b = i >> 10, d = i & 1023;
  float s = 0.f;
  #pragma unroll
  for (int cc = 0; cc < 16; ++cc) s += ctxp[((size_t)((b << 4) + cc) << 10) + d];
  out[i] = s;
}

// ---- fp32-path K4/K5 ------------------------------------------------------
__global__ void k4_ctx_f32(const float* __restrict__ mem, const float* __restrict__ weights,
                           float* __restrict__ ctxp) {
  int nc = blockIdx.x, b = blockIdx.y;
  int d = threadIdx.x << 3;
  floatx4 a0 = {0.f, 0.f, 0.f, 0.f}, a1 = {0.f, 0.f, 0.f, 0.f};
  int nbase = nc << 6;
  for (int n = nbase; n < nbase + 64; ++n) {
    float wv = weights[(b << 9) + n];
    const floatx4* p = (const floatx4*)(mem + ((size_t)((b << 9) + n) << 10) + d);
    a0 += wv * p[0];
    a1 += wv * p[1];
  }
  floatx4* o = (floatx4*)(ctxp + ((size_t)((b << 3) + nc) << 10) + d);
  o[0] = a0;
  o[1] = a1;
}

__global__ void k5_reduce8(const float* __restrict__ ctxp, float* __restrict__ out) {
  int i = (blockIdx.x << 8) + threadIdx.x;
  int b = i >> 10, d = i & 1023;
  float s = 0.f;
  #pragma unroll
  for (int cc = 0; cc < 8; ++cc) s += ctxp[((size_t)((b << 3) + cc) << 10) + d];
  out[i] = s;
}

extern "C" void kernel_launch(void* const* d_in, const int* in_sizes, int n_in,
                              void* d_out, int out_size, void* d_ws, size_t ws_size,
                              hipStream_t stream) {
  const float* mem = (const float*)d_in[0];   // (64,512,1024) fp32
  const int* mask = (const int*)d_in[1];      // (64,512) int32
  const float* query = (const float*)d_in[2]; // (64,1024) fp32
  const float* Wh = (const float*)d_in[3];    // (1024,1024) fp32
  const float* Ws = (const float*)d_in[4];    // (1024,1024) fp32
  const float* v = (const float*)d_in[5];     // (1024,1) fp32
  float* out = (float*)d_out;                 // (64,1024) fp32

  char* ws = (char*)d_ws;
  const size_t need16 = (73ull << 20);

  if (ws_size >= need16) {
    _Float16* memh = (_Float16*)ws;                                    // 64 MiB
    _Float16* WhT = (_Float16*)(ws + (64ull << 20));                   // 2 MiB
    float* partials = (float*)(ws + (66ull << 20));                    // 2 MiB
    float* tq = (float*)(ws + (68ull << 20));                          // 256 KiB
    float* weights = (float*)(ws + (68ull << 20) + (256 << 10));       // 128 KiB
    float* ctxp = (float*)(ws + (69ull << 20));                        // 4 MiB

    static int use8 = -1;
    if (use8 < 0) {
      use8 = (hipFuncSetAttribute((const void*)k2_8ph,
                                  hipFuncAttributeMaxDynamicSharedMemorySize,
                                  131072) == hipSuccess) ? 1 : 0;
    }

    k_prep<<<17664, 256, 0, stream>>>(mem, memh, Wh, WhT, query, Ws, tq);
    if (use8)
      k2_8ph<<<512, 512, 131072, stream>>>(memh, WhT, tq, v, partials);
    else
      k2_gemm_h<<<2048, 256, 0, stream>>>(memh, WhT, tq, v, partials);
    k3_softmax<<<64, 512, 0, stream>>>(partials, mask, weights);
    k4_ctx_h<<<dim3(16, 64), 128, 0, stream>>>(memh, weights, ctxp);
    k5_reduce16<<<256, 256, 0, stream>>>(ctxp, out);
  } else {
    _Float16* WhT = (_Float16*)ws;                                     // 2 MiB
    float* partials = (float*)(ws + ((size_t)2 << 20));                // 2 MiB
    float* tq = (float*)(ws + ((size_t)4 << 20));                      // 256 KiB
    float* weights = (float*)(ws + ((size_t)4 << 20) + (256 << 10));   // 128 KiB
    float* ctxp = (float*)(ws + ((size_t)9 << 19));                    // 2 MiB

    k0_transpose<<<dim3(16, 16), dim3(64, 4), 0, stream>>>(Wh, WhT);
    k1_tq<<<dim3(16, 64), 256, 0, stream>>>(query, Ws, tq);
    k2_gemm_f32<<<2048, 256, 0, stream>>>(mem, WhT, tq, v, partials);
    k3_softmax<<<64, 512, 0, stream>>>(partials, mask, weights);
    k4_ctx_f32<<<dim3(8, 64), 128, 0, stream>>>(mem, weights, ctxp);
    k5_reduce8<<<256, 256, 0, stream>>>(ctxp, out);
  }
}

// Round 4
// 295.063 us; speedup vs baseline: 1.0549x; 1.0204x over previous
//
#include <hip/hip_runtime.h>
#include <cstdint>
#include <cstddef>

typedef float floatx4 __attribute__((ext_vector_type(4)));
typedef _Float16 half8_t __attribute__((ext_vector_type(8)));
typedef _Float16 half2_t __attribute__((ext_vector_type(2)));

#define AS1 __attribute__((address_space(1)))
#define AS3 __attribute__((address_space(3)))

__device__ __forceinline__ void glds16(const void* g, void* l) {
  __builtin_amdgcn_global_load_lds((const AS1 void*)g, (AS3 void*)l, 16, 0, 0);
}

__device__ __forceinline__ half2_t pkrtz(float a, float b) {
  return __builtin_bit_cast(half2_t, __builtin_amdgcn_cvt_pkrtz(a, b));
}

__device__ __forceinline__ float fast_tanh(float x) {
  // tanh(x) = 1 - 2/(e^{2x}+1); inf-safe (e2=inf -> rcp=0 -> 1; e2=0 -> -1)
  float e2 = __expf(2.f * x);
  return 1.f - 2.f * __builtin_amdgcn_rcpf(e2 + 1.f);
}

// ---- k_prep: fused {Wh transpose->f16 | tq = q@Ws | memf32->f16 cvt} ------
// Long-latency small-grid work FIRST so it overlaps the cvt stream:
// blocks [0,256): transpose ; [256,1280): tq ; [1280,17664): cvt
__global__ __launch_bounds__(256) void k_prep(
    const float* __restrict__ mem, _Float16* __restrict__ memh,
    const float* __restrict__ Wh, _Float16* __restrict__ WhT,
    const float* __restrict__ q, const float* __restrict__ Ws,
    float* __restrict__ tq) {
  __shared__ float sh[64 * 65];
  const int bx = blockIdx.x;
  const int tid = threadIdx.x;
  if (bx >= 1280) {
    size_t i = (((size_t)(bx - 1280) << 8) + tid) << 3;
    floatx4 a = *(const floatx4*)(mem + i);
    floatx4 b = *(const floatx4*)(mem + i + 4);
    union { half2_t h2[4]; half8_t h8; } u;
    u.h2[0] = half2_t{(_Float16)a[0], (_Float16)a[1]};
    u.h2[1] = half2_t{(_Float16)a[2], (_Float16)a[3]};
    u.h2[2] = half2_t{(_Float16)b[0], (_Float16)b[1]};
    u.h2[3] = half2_t{(_Float16)b[2], (_Float16)b[3]};
    *(half8_t*)(memh + i) = u.h8;
  } else if (bx < 256) {
    int bb = bx;
    int n0 = (bb & 15) << 6, k0 = (bb >> 4) << 6;
    int tx = tid & 63, ty = tid >> 6;
    #pragma unroll
    for (int r = ty; r < 64; r += 4) sh[r * 65 + tx] = Wh[(size_t)(k0 + r) * 1024 + n0 + tx];
    __syncthreads();
    #pragma unroll
    for (int r = ty; r < 64; r += 4)
      WhT[(size_t)(n0 + r) * 1024 + k0 + tx] = (_Float16)sh[tx * 65 + r];
  } else {
    int bb = bx - 256;
    int d0 = (bb & 15) << 6, b = bb >> 4;
    int dl = tid & 63, kg = tid >> 6;
    float* qs = sh;
    float* red = sh + 1024;  // [4][64]
    for (int k = tid; k < 1024; k += 256) qs[k] = q[(b << 10) + k];
    __syncthreads();
    float acc = 0.f;
    int kbase = kg << 8;
    #pragma unroll 8
    for (int k = 0; k < 256; ++k)
      acc += qs[kbase + k] * Ws[(size_t)(kbase + k) * 1024 + d0 + dl];
    red[(kg << 6) + dl] = acc;
    __syncthreads();
    if (kg == 0)
      tq[(b << 10) + d0 + dl] = red[dl] + red[64 + dl] + red[128 + dl] + red[192 + dl];
  }
}

// ---- K0/K1 standalone (small-ws fallback path) ----------------------------
__global__ void k0_transpose(const float* __restrict__ Wh, _Float16* __restrict__ WhT) {
  __shared__ float t[64][65];
  int k0 = blockIdx.y << 6, n0 = blockIdx.x << 6;
  int tx = threadIdx.x, ty = threadIdx.y;
  #pragma unroll
  for (int r = ty; r < 64; r += 4) t[r][tx] = Wh[(size_t)(k0 + r) * 1024 + n0 + tx];
  __syncthreads();
  #pragma unroll
  for (int r = ty; r < 64; r += 4)
    WhT[(size_t)(n0 + r) * 1024 + k0 + tx] = (_Float16)t[tx][r];
}

__global__ __launch_bounds__(256) void k1_tq(const float* __restrict__ q,
                                             const float* __restrict__ Ws,
                                             float* __restrict__ tq) {
  __shared__ float qs[1024];
  __shared__ float red[4][64];
  int b = blockIdx.y;
  int d0 = blockIdx.x << 6;
  int dl = threadIdx.x & 63, kg = threadIdx.x >> 6;
  for (int k = threadIdx.x; k < 1024; k += 256) qs[k] = q[(b << 10) + k];
  __syncthreads();
  float acc = 0.f;
  int kbase = kg << 8;
  #pragma unroll 8
  for (int k = 0; k < 256; ++k)
    acc += qs[kbase + k] * Ws[(size_t)(kbase + k) * 1024 + d0 + dl];
  red[kg][dl] = acc;
  __syncthreads();
  if (kg == 0)
    tq[(b << 10) + d0 + dl] = red[0][dl] + red[1][dl] + red[2][dl] + red[3][dl];
}

// ---- K2 fine-phase deep-pipe: 256x256 tile, BK=64, 8 waves ----------------
// A = memh (32768x1024 f16), BT = WhT (1024x1024 f16 n-major).
// LDS (128 KiB dynamic):
//   A: buf*32768 + (wm*2+rh)*8192 + r6*128 + chunk*16        (r6 in [0,64))
//   B: 65536 + buf*32768 + ch*16384 + wn*4096 + r5*128 + c*16
// Swizzle: chunk_stored = chunk_logical ^ (row & 7) via inverse-swz global
// source (glds dest stays linear); swz applied on the ds_read side.
// m201-style 4-phase/K-tile quadrant schedule. Per phase:
//   [ds_reads for THIS phase's MFMA quadrant] [vmcnt gate for data first
//   read ONE phase later] [stage half-tiles of tile t+1] [open barrier]
//   [setprio 16xMFMA] [close barrier]
// Ledger (steady state, per K-tile): stages {4,2,2,0} loads at P1..P4;
// gates VM(2)@P1, VM(4)@P2, none@P3, VM(4)@P4 — each gate waits only on
// loads issued >=3 phases earlier and is separated from the protected
// cross-wave ds_read by >=1 barrier. Never drains below 2 in flight.
__global__ __launch_bounds__(512, 2) void k2_8ph(
    const _Float16* __restrict__ Ah, const _Float16* __restrict__ BT,
    const float* __restrict__ tq, const float* __restrict__ v,
    float* __restrict__ partials) {
  extern __shared__ char smem[];
  const int bid = blockIdx.x;
  const int wg = ((bid & 7) << 6) | (bid >> 3);  // bijective XCD swizzle (512 wgs)
  const int mtile = wg >> 2, ntile = wg & 3;
  const int m0 = mtile << 8, n0 = ntile << 8;
  const int tid = threadIdx.x;
  const int w = tid >> 6, lane = tid & 63;
  const int wm = w >> 2, wn = w & 3, quad = lane >> 4, l15 = lane & 15;

  // ds_read byte offsets (sans buf/rh/ch bases)
  int aoff[2][4], boff[2][2];
  #pragma unroll
  for (int ks = 0; ks < 2; ++ks) {
    int swz = ((ks << 2) + quad) ^ (l15 & 7);
    #pragma unroll
    for (int i = 0; i < 4; ++i)
      aoff[ks][i] = (wm << 14) + (((i << 4) + l15) << 7) + (swz << 4);
    #pragma unroll
    for (int j = 0; j < 2; ++j)
      boff[ks][j] = 65536 + (wn << 12) + (((j << 4) + l15) << 7) + (swz << 4);
  }

  // staging: per-thread global src offsets (f16 elems) + wave-uniform LDS dst
  const int rr = tid >> 3, cc = tid & 7;
  const int r5 = rr & 31;
  int aSrc[2][2], bSrc[2][2], dA[2][2], dB[2][2];
  #pragma unroll
  for (int h = 0; h < 2; ++h)
    #pragma unroll
    for (int hm = 0; hm < 2; ++hm) {
      aSrc[h][hm] = ((m0 + (hm << 7) + (h << 6) + rr) << 10) + ((cc ^ (rr & 7)) << 3);
      dA[h][hm] = (((hm << 1) + h) << 13) + (w << 10);
    }
  #pragma unroll
  for (int ch = 0; ch < 2; ++ch)
    #pragma unroll
    for (int is = 0; is < 2; ++is) {
      int wnb = (is << 1) + (rr >> 5);
      bSrc[ch][is] = ((n0 + (wnb << 6) + (ch << 5) + r5) << 10) + ((cc ^ (r5 & 7)) << 3);
      dB[ch][is] = 65536 + (ch << 14) + (is << 13) + (w << 10);
    }

  floatx4 acc[8][4];
  #pragma unroll
  for (int i = 0; i < 8; ++i)
    #pragma unroll
    for (int j = 0; j < 4; ++j) acc[i][j] = floatx4{0.f, 0.f, 0.f, 0.f};

  half8_t af[2][4], bf[2][2][2];

#define STAGE_A(H, KST, OO)                                   \
  glds16(Ah + aSrc[H][0] + (KST), smem + (OO) + dA[H][0]);    \
  glds16(Ah + aSrc[H][1] + (KST), smem + (OO) + dA[H][1]);
#define STAGE_B(CH, KST, OO)                                  \
  glds16(BT + bSrc[CH][0] + (KST), smem + (OO) + dB[CH][0]);  \
  glds16(BT + bSrc[CH][1] + (KST), smem + (OO) + dB[CH][1]);
#define VM(N) asm volatile("s_waitcnt vmcnt(" #N ")" ::: "memory");
#define BAR __builtin_amdgcn_s_barrier();
#define LOAD_AF(CO, RHOFF)                                    \
  _Pragma("unroll")                                           \
  for (int ks_ = 0; ks_ < 2; ++ks_) {                         \
    _Pragma("unroll")                                         \
    for (int i_ = 0; i_ < 4; ++i_)                            \
      af[ks_][i_] = *(const half8_t*)(smem + (CO) + (RHOFF) + aoff[ks_][i_]); \
  }
#define LOAD_BF(CH, CO, CHOFF)                                \
  _Pragma("unroll")                                           \
  for (int ks_ = 0; ks_ < 2; ++ks_) {                         \
    _Pragma("unroll")                                         \
    for (int j_ = 0; j_ < 2; ++j_)                            \
      bf[CH][ks_][j_] = *(const half8_t*)(smem + (CO) + (CHOFF) + boff[ks_][j_]); \
  }
#define MFMAS(RH, CH)                                         \
  _Pragma("unroll")                                           \
  for (int ks_ = 0; ks_ < 2; ++ks_) {                         \
    _Pragma("unroll")                                         \
    for (int i_ = 0; i_ < 4; ++i_) {                          \
      _Pragma("unroll")                                       \
      for (int j_ = 0; j_ < 2; ++j_)                          \
        acc[(RH)*4 + i_][(CH)*2 + j_] = __builtin_amdgcn_mfma_f32_16x16x32_f16( \
            af[ks_][i_], bf[CH][ks_][j_], acc[(RH)*4 + i_][(CH)*2 + j_], 0, 0, 0); \
    }                                                         \
  }
#define PRIO_MFMA(RH, CH)                                     \
  __builtin_amdgcn_s_setprio(1);                              \
  MFMAS(RH, CH)                                               \
  __builtin_amdgcn_s_setprio(0);
// One K-tile = 4 phases (quadrants Q(rh,ch)); reads {12,4,8,0}; stages
// {4,2,2,0}; gates VM(2)/VM(4)/-/VM(4).
#define GROUPT(CO, OO, KST)                                   \
  /* P1: Q(0,0) */                                            \
  LOAD_AF(CO, 0)                                              \
  LOAD_BF(0, CO, 0)                                           \
  VM(2)                                                       \
  STAGE_A(0, KST, OO)                                         \
  STAGE_B(0, KST, OO)                                         \
  BAR                                                         \
  PRIO_MFMA(0, 0)                                             \
  BAR                                                         \
  /* P2: Q(0,1) */                                            \
  LOAD_BF(1, CO, 16384)                                       \
  VM(4)                                                       \
  STAGE_B(1, KST, OO)                                         \
  BAR                                                         \
  PRIO_MFMA(0, 1)                                             \
  BAR                                                         \
  /* P3: Q(1,0) */                                            \
  LOAD_AF(CO, 8192)                                           \
  STAGE_A(1, KST, OO)                                         \
  BAR                                                         \
  PRIO_MFMA(1, 0)                                             \
  BAR                                                         \
  /* P4: Q(1,1) */                                            \
  VM(4)                                                       \
  BAR                                                         \
  PRIO_MFMA(1, 1)                                             \
  BAR

  // prologue: stage tile 0 -> buf0; ensure A0[h0],B0[c0] landed, leave
  // B0[c1],A0[h1] (4 loads) in flight -> steady-state ledger entry.
  STAGE_A(0, 0, 0)
  STAGE_B(0, 0, 0)
  STAGE_B(1, 0, 0)
  STAGE_A(1, 0, 0)
  VM(4)
  BAR

  #pragma unroll 1
  for (int g2 = 0; g2 < 8; ++g2) {
    const int g = g2 << 1;
    const int kst1 = (g + 1) << 6;
    const int kst2 = (g2 == 7) ? (15 << 6) : ((g + 2) << 6);  // clamp: redundant last stage keeps ledger uniform
    GROUPT(0, 32768, kst1)
    GROUPT(32768, 0, kst2)
  }

#undef GROUPT
#undef PRIO_MFMA
#undef MFMAS
#undef LOAD_BF
#undef LOAD_AF
#undef BAR
#undef VM
#undef STAGE_B
#undef STAGE_A

  // drain in-flight DMA before the block can exit / LDS reuse
  asm volatile("s_waitcnt vmcnt(0)" ::: "memory");

  // epilogue: tanh(acc + tq) . v, reduce across 16 lanes, write partials
  const int b = m0 >> 9;
  const int colb = n0 + (wn << 6) + l15;
  float tqv[4], vv[4];
  #pragma unroll
  for (int jf = 0; jf < 4; ++jf) {
    int n = colb + (jf << 4);
    tqv[jf] = tq[(b << 10) + n];
    vv[jf] = v[n];
  }
  #pragma unroll
  for (int rf = 0; rf < 8; ++rf) {
    #pragma unroll
    for (int r = 0; r < 4; ++r) {
      float s = 0.f;
      #pragma unroll
      for (int jf = 0; jf < 4; ++jf) s += fast_tanh(acc[rf][jf][r] + tqv[jf]) * vv[jf];
      s += __shfl_xor(s, 1);
      s += __shfl_xor(s, 2);
      s += __shfl_xor(s, 4);
      s += __shfl_xor(s, 8);
      if (l15 == 0) {
        int m = m0 + (wm << 7) + (rf << 4) + (quad << 2) + r;
        partials[m * 16 + (ntile << 2) + wn] = s;
      }
    }
  }
}

// ---- K2 m97-structure fallback (if 128K dyn-LDS attr refused) -------------
__global__ __launch_bounds__(256, 2) void k2_gemm_h(
    const _Float16* __restrict__ Ah, const _Float16* __restrict__ BT,
    const float* __restrict__ tq, const float* __restrict__ v,
    float* __restrict__ partials) {
  __shared__ _Float16 As[128 * 32];
  __shared__ _Float16 Bs[128 * 32];
  const int bid = blockIdx.x;
  const int mtile = ((bid >> 6) << 3) | (bid & 7);
  const int nblk = (bid >> 3) & 7;
  const int m0 = mtile << 7, n0 = nblk << 7;
  const int tid = threadIdx.x;
  const int w = tid >> 6, lane = tid & 63;
  const int wm = w >> 1, wn = w & 1, quad = lane >> 4, l15 = lane & 15;

  floatx4 acc[4][4];
  #pragma unroll
  for (int i = 0; i < 4; ++i)
    #pragma unroll
    for (int j = 0; j < 4; ++j) acc[i][j] = floatx4{0.f, 0.f, 0.f, 0.f};

  const _Float16 *gA[2], *gB[2];
  _Float16 *lA[2], *lB[2];
  #pragma unroll
  for (int t = 0; t < 2; ++t) {
    int L = (t << 8) + (w << 6) + lane;
    int row = L >> 2, jj = L & 3;
    int j = (jj - row - (row >> 2)) & 3;
    gA[t] = Ah + (size_t)(m0 + row) * 1024 + (j << 3);
    gB[t] = BT + (size_t)(n0 + row) * 1024 + (j << 3);
    lA[t] = As + (t << 11) + (w << 9);
    lB[t] = Bs + (t << 11) + (w << 9);
  }

  const half8_t *aaddr[4], *baddr[4];
  #pragma unroll
  for (int i = 0; i < 4; ++i) {
    int ar = (wm << 6) + (i << 4) + l15;
    aaddr[i] = (const half8_t*)(As + (ar << 5) + (((quad + ar + (ar >> 2)) & 3) << 3));
    int br = (wn << 6) + (i << 4) + l15;
    baddr[i] = (const half8_t*)(Bs + (br << 5) + (((quad + br + (br >> 2)) & 3) << 3));
  }

  for (int k0 = 0; k0 < 1024; k0 += 32) {
    __syncthreads();
    glds16(gA[0] + k0, lA[0]);
    glds16(gA[1] + k0, lA[1]);
    glds16(gB[0] + k0, lB[0]);
    glds16(gB[1] + k0, lB[1]);
    __syncthreads();
    half8_t af[4], bfr[4];
    #pragma unroll
    for (int i = 0; i < 4; ++i) af[i] = *aaddr[i];
    #pragma unroll
    for (int j = 0; j < 4; ++j) bfr[j] = *baddr[j];
    #pragma unroll
    for (int i = 0; i < 4; ++i)
      #pragma unroll
      for (int j = 0; j < 4; ++j)
        acc[i][j] = __builtin_amdgcn_mfma_f32_16x16x32_f16(af[i], bfr[j], acc[i][j], 0, 0, 0);
  }

  const int b = m0 >> 9;
  const int colbase = n0 + (wn << 6) + l15;
  float tqv[4], vv[4];
  #pragma unroll
  for (int j = 0; j < 4; ++j) {
    int n = colbase + (j << 4);
    tqv[j] = tq[(b << 10) + n];
    vv[j] = v[n];
  }
  #pragma unroll
  for (int i = 0; i < 4; ++i) {
    #pragma unroll
    for (int r = 0; r < 4; ++r) {
      float s = 0.f;
      #pragma unroll
      for (int j = 0; j < 4; ++j) s += fast_tanh(acc[i][j][r] + tqv[j]) * vv[j];
      s += __shfl_xor(s, 1);
      s += __shfl_xor(s, 2);
      s += __shfl_xor(s, 4);
      s += __shfl_xor(s, 8);
      if (l15 == 0) {
        int m = m0 + (wm << 6) + (i << 4) + (quad << 2) + r;
        partials[m * 16 + (nblk << 1) + wn] = s;
      }
    }
  }
}

// ---- K2 fallback (fp32 A staging) — small-ws verified path ----------------
__global__ __launch_bounds__(256, 2) void k2_gemm_f32(
    const float* __restrict__ A, const _Float16* __restrict__ BT,
    const float* __restrict__ tq, const float* __restrict__ v,
    float* __restrict__ partials) {
  __shared__ float As[128 * 32];
  __shared__ _Float16 Bs[128 * 32];
  const int bid = blockIdx.x;
  const int mtile = ((bid >> 6) << 3) | (bid & 7);
  const int nblk = (bid >> 3) & 7;
  const int m0 = mtile << 7, n0 = nblk << 7;
  const int tid = threadIdx.x;
  const int w = tid >> 6, lane = tid & 63;
  const int wm = w >> 1, wn = w & 1, quad = lane >> 4, l15 = lane & 15;

  floatx4 acc[4][4];
  #pragma unroll
  for (int i = 0; i < 4; ++i)
    #pragma unroll
    for (int j = 0; j < 4; ++j) acc[i][j] = floatx4{0.f, 0.f, 0.f, 0.f};

  const float* gA[4];
  float* lA[4];
  #pragma unroll
  for (int t = 0; t < 4; ++t) {
    int L = (t << 8) + (w << 6) + lane;
    int row = L >> 3, jj = L & 7;
    int j = (jj - row) & 7;
    gA[t] = A + (size_t)(m0 + row) * 1024 + (j << 2);
    lA[t] = As + (t << 10) + (w << 8);
  }
  const _Float16* gB[2];
  _Float16* lB[2];
  #pragma unroll
  for (int t = 0; t < 2; ++t) {
    int L = (t << 8) + (w << 6) + lane;
    int row = L >> 2, jj = L & 3;
    int j = (jj - row - (row >> 2)) & 3;
    gB[t] = BT + (size_t)(n0 + row) * 1024 + (j << 3);
    lB[t] = Bs + (t << 11) + (w << 9);
  }
  const floatx4* aaddr[4][2];
  #pragma unroll
  for (int i = 0; i < 4; ++i) {
    int row = (wm << 6) + (i << 4) + l15;
    #pragma unroll
    for (int h = 0; h < 2; ++h) {
      int pos = ((quad << 1) + h + row) & 7;
      aaddr[i][h] = (const floatx4*)(As + (row << 5) + (pos << 2));
    }
  }
  const half8_t* baddr[4];
  #pragma unroll
  for (int j = 0; j < 4; ++j) {
    int row = (wn << 6) + (j << 4) + l15;
    int pos = (quad + row + (row >> 2)) & 3;
    baddr[j] = (const half8_t*)(Bs + (row << 5) + (pos << 3));
  }
  for (int k0 = 0; k0 < 1024; k0 += 32) {
    __syncthreads();
    glds16(gA[0] + k0, lA[0]);
    glds16(gA[1] + k0, lA[1]);
    glds16(gA[2] + k0, lA[2]);
    glds16(gA[3] + k0, lA[3]);
    glds16(gB[0] + k0, lB[0]);
    glds16(gB[1] + k0, lB[1]);
    __syncthreads();
    half8_t af[4], bfr[4];
    #pragma unroll
    for (int i = 0; i < 4; ++i) {
      floatx4 x = *aaddr[i][0], y = *aaddr[i][1];
      union { half2_t h2[4]; half8_t h8; } u;
      u.h2[0] = pkrtz(x[0], x[1]);
      u.h2[1] = pkrtz(x[2], x[3]);
      u.h2[2] = pkrtz(y[0], y[1]);
      u.h2[3] = pkrtz(y[2], y[3]);
      af[i] = u.h8;
    }
    #pragma unroll
    for (int j = 0; j < 4; ++j) bfr[j] = *baddr[j];
    #pragma unroll
    for (int i = 0; i < 4; ++i)
      #pragma unroll
      for (int j = 0; j < 4; ++j)
        acc[i][j] = __builtin_amdgcn_mfma_f32_16x16x32_f16(af[i], bfr[j], acc[i][j], 0, 0, 0);
  }
  const int b = m0 >> 9;
  const int colbase = n0 + (wn << 6) + l15;
  float tqv[4], vv[4];
  #pragma unroll
  for (int j = 0; j < 4; ++j) {
    int n = colbase + (j << 4);
    tqv[j] = tq[(b << 10) + n];
    vv[j] = v[n];
  }
  #pragma unroll
  for (int i = 0; i < 4; ++i) {
    #pragma unroll
    for (int r = 0; r < 4; ++r) {
      float s = 0.f;
      #pragma unroll
      for (int j = 0; j < 4; ++j) s += fast_tanh(acc[i][j][r] + tqv[j]) * vv[j];
      s += __shfl_xor(s, 1);
      s += __shfl_xor(s, 2);
      s += __shfl_xor(s, 4);
      s += __shfl_xor(s, 8);
      if (l15 == 0) {
        int m = m0 + (wm << 6) + (i << 4) + (quad << 2) + r;
        partials[m * 16 + (nblk << 1) + wn] = s;
      }
    }
  }
}

// ---- K3: masked softmax over N=512 per batch ------------------------------
__global__ __launch_bounds__(512) void k3_softmax(const float* __restrict__ partials,
                                                  const int* __restrict__ mask,
                                                  float* __restrict__ weights) {
  int b = blockIdx.x;
  int n = threadIdx.x;
  int m = (b << 9) + n;
  float s = 0.f;
  #pragma unroll
  for (int i = 0; i < 16; ++i) s += partials[m * 16 + i];
  int mk = mask[m];
  float logit = mk ? s : -1e30f;
  __shared__ float red[8];
  float x = logit;
  #pragma unroll
  for (int off = 32; off > 0; off >>= 1) x = fmaxf(x, __shfl_xor(x, off));
  if ((n & 63) == 0) red[n >> 6] = x;
  __syncthreads();
  float mx = red[0];
  #pragma unroll
  for (int i = 1; i < 8; ++i) mx = fmaxf(mx, red[i]);
  float e = mk ? __expf(logit - mx) : 0.f;
  float ss = e;
  #pragma unroll
  for (int off = 32; off > 0; off >>= 1) ss += __shfl_xor(ss, off);
  __syncthreads();
  if ((n & 63) == 0) red[n >> 6] = ss;
  __syncthreads();
  float tot = 0.f;
  #pragma unroll
  for (int i = 0; i < 8; ++i) tot += red[i];
  weights[m] = (tot > 0.f) ? e / tot : 0.f;
}

// ---- K4 (fp16 mem): context partials over 32-row chunks, grid (16,64) -----
__global__ void k4_ctx_h(const _Float16* __restrict__ memh,
                         const float* __restrict__ weights, float* __restrict__ ctxp) {
  int nc = blockIdx.x, b = blockIdx.y;
  int d = threadIdx.x << 3;
  float acc[8] = {0.f, 0.f, 0.f, 0.f, 0.f, 0.f, 0.f, 0.f};
  int nbase = nc << 5;
  for (int n = nbase; n < nbase + 32; ++n) {
    float wv = weights[(b << 9) + n];
    half8_t x = *(const half8_t*)(memh + ((size_t)((b << 9) + n) << 10) + d);
    #pragma unroll
    for (int k = 0; k < 8; ++k) acc[k] += wv * (float)x[k];
  }
  float* o = ctxp + ((size_t)((b << 4) + nc) << 10) + d;
  #pragma unroll
  for (int k = 0; k < 8; ++k) o[k] = acc[k];
}

__global__ void k5_reduce16(const float* __restrict__ ctxp, float* __restrict__ out) {
  int i = (blockIdx.x << 8) + threadIdx.x;
  int b = i >> 10, d = i & 1023;
  float s = 0.f;
  #pragma unroll
  for (int cc = 0; cc < 16; ++cc) s += ctxp[((size_t)((b << 4) + cc) << 10) + d];
  out[i] = s;
}

// ---- fp32-path K4/K5 ------------------------------------------------------
__global__ void k4_ctx_f32(const float* __restrict__ mem, const float* __restrict__ weights,
                           float* __restrict__ ctxp) {
  int nc = blockIdx.x, b = blockIdx.y;
  int d = threadIdx.x << 3;
  floatx4 a0 = {0.f, 0.f, 0.f, 0.f}, a1 = {0.f, 0.f, 0.f, 0.f};
  int nbase = nc << 6;
  for (int n = nbase; n < nbase + 64; ++n) {
    float wv = weights[(b << 9) + n];
    const floatx4* p = (const floatx4*)(mem + ((size_t)((b << 9) + n) << 10) + d);
    a0 += wv * p[0];
    a1 += wv * p[1];
  }
  floatx4* o = (floatx4*)(ctxp + ((size_t)((b << 3) + nc) << 10) + d);
  o[0] = a0;
  o[1] = a1;
}

__global__ void k5_reduce8(const float* __restrict__ ctxp, float* __restrict__ out) {
  int i = (blockIdx.x << 8) + threadIdx.x;
  int b = i >> 10, d = i & 1023;
  float s = 0.f;
  #pragma unroll
  for (int cc = 0; cc < 8; ++cc) s += ctxp[((size_t)((b << 3) + cc) << 10) + d];
  out[i] = s;
}

extern "C" void kernel_launch(void* const* d_in, const int* in_sizes, int n_in,
                              void* d_out, int out_size, void* d_ws, size_t ws_size,
                              hipStream_t stream) {
  const float* mem = (const float*)d_in[0];   // (64,512,1024) fp32
  const int* mask = (const int*)d_in[1];      // (64,512) int32
  const float* query = (const float*)d_in[2]; // (64,1024) fp32
  const float* Wh = (const float*)d_in[3];    // (1024,1024) fp32
  const float* Ws = (const float*)d_in[4];    // (1024,1024) fp32
  const float* v = (const float*)d_in[5];     // (1024,1) fp32
  float* out = (float*)d_out;                 // (64,1024) fp32

  char* ws = (char*)d_ws;
  const size_t need16 = (73ull << 20);

  if (ws_size >= need16) {
    _Float16* memh = (_Float16*)ws;                                    // 64 MiB
    _Float16* WhT = (_Float16*)(ws + (64ull << 20));                   // 2 MiB
    float* partials = (float*)(ws + (66ull << 20));                    // 2 MiB
    float* tq = (float*)(ws + (68ull << 20));                          // 256 KiB
    float* weights = (float*)(ws + (68ull << 20) + (256 << 10));       // 128 KiB
    float* ctxp = (float*)(ws + (69ull << 20));                        // 4 MiB

    static int use8 = -1;
    if (use8 < 0) {
      use8 = (hipFuncSetAttribute((const void*)k2_8ph,
                                  hipFuncAttributeMaxDynamicSharedMemorySize,
                                  131072) == hipSuccess) ? 1 : 0;
    }

    k_prep<<<17664, 256, 0, stream>>>(mem, memh, Wh, WhT, query, Ws, tq);
    if (use8)
      k2_8ph<<<512, 512, 131072, stream>>>(memh, WhT, tq, v, partials);
    else
      k2_gemm_h<<<2048, 256, 0, stream>>>(memh, WhT, tq, v, partials);
    k3_softmax<<<64, 512, 0, stream>>>(partials, mask, weights);
    k4_ctx_h<<<dim3(16, 64), 128, 0, stream>>>(memh, weights, ctxp);
    k5_reduce16<<<256, 256, 0, stream>>>(ctxp, out);
  } else {
    _Float16* WhT = (_Float16*)ws;                                     // 2 MiB
    float* partials = (float*)(ws + ((size_t)2 << 20));                // 2 MiB
    float* tq = (float*)(ws + ((size_t)4 << 20));                      // 256 KiB
    float* weights = (float*)(ws + ((size_t)4 << 20) + (256 << 10));   // 128 KiB
    float* ctxp = (float*)(ws + ((size_t)9 << 19));                    // 2 MiB

    k0_transpose<<<dim3(16, 16), dim3(64, 4), 0, stream>>>(Wh, WhT);
    k1_tq<<<dim3(16, 64), 256, 0, stream>>>(query, Ws, tq);
    k2_gemm_f32<<<2048, 256, 0, stream>>>(mem, WhT, tq, v, partials);
    k3_softmax<<<64, 512, 0, stream>>>(partials, mask, weights);
    k4_ctx_f32<<<dim3(8, 64), 128, 0, stream>>>(mem, weights, ctxp);
    k5_reduce8<<<256, 256, 0, stream>>>(ctxp, out);
  }
}